// Round 1
// baseline (1193.114 us; speedup 1.0000x reference)
//
#include <hip/hip_runtime.h>

typedef unsigned short u16;
typedef __attribute__((ext_vector_type(8))) __bf16 bf16x8;
typedef __attribute__((ext_vector_type(4))) float f32x4;

#define BB 8
#define TT 96
#define NN 20000
#define PP 12
#define LL 3
#define DD 32
#define CC 128
#define MM 64
#define KV_PITCH 132
#define NBLK 32
#define ROWS 640

constexpr float KSC  = 0.8408964152537145f;   // 2 * 32^-0.25  (inv_sqrt_tau * d^-0.25)
constexpr float KSC2 = 0.7071067811865476f;   // KSC^2

__device__ inline u16 f2bf(float f){
  unsigned u = __float_as_uint(f);
  u = (u + 0x7fffu + ((u >> 16) & 1u)) >> 16;
  return (u16)u;
}
__device__ inline float bf2f(u16 h){ return __uint_as_float(((unsigned)h) << 16); }
__device__ inline unsigned fmapu(float f){
  unsigned u = __float_as_uint(f);
  return (u & 0x80000000u) ? ~u : (u | 0x80000000u);
}
__device__ inline float funmap(unsigned u){
  return (u & 0x80000000u) ? __uint_as_float(u & 0x7fffffffu) : __uint_as_float(~u);
}
__device__ inline unsigned pk2(float a, float b){
  return (unsigned)f2bf(a) | ((unsigned)f2bf(b) << 16);
}

// ---------------- K0: per-batch scalars -------------------------------------
__global__ void k0_prep(const float* xm, const float* time_tab, const float* week_tab,
                        const float* w1w, const float* w1b, const float* w2w, const float* w2b,
                        const float* inw, const float* inb, const float* proj,
                        float* bv1, float* bv2, float* sbd1, float* sbd2,
                        float* bc1, float* bc2, float* mb, int* tod, int* dow,
                        unsigned* cmx)
{
  __shared__ float sT[BB][DD], sWk[BB][DD];
  __shared__ float sB1[BB][DD], sB2[BB][DD];
  __shared__ int sTod[BB], sDow[BB];
  int tid = threadIdx.x;  // 512
  if (tid < BB){
    float t0 = xm[(tid*TT + TT-1)*2 + 0];
    float t1 = xm[(tid*TT + TT-1)*2 + 1];
    int ti = (int)(t0 * (float)TT); ti = min(max(ti, 0), TT-1);
    int di = (int)(t1 * 7.0f);      di = min(max(di, 0), 6);
    sTod[tid] = ti; sDow[tid] = di; tod[tid] = ti; dow[tid] = di;
  }
  if (tid < MM) cmx[tid] = fmapu(-3e38f);
  __syncthreads();
  if (tid < BB*DD){
    int b = tid >> 5, g = tid & 31;
    sT[b][g]  = time_tab[sTod[b]*DD + g];
    sWk[b][g] = week_tab[sDow[b]*DD + g];
  }
  __syncthreads();
  {
    int which = tid >> 8, b = (tid >> 5) & 7, c = tid & 31;
    const float* w  = which ? w2w : w1w;
    const float* wb = which ? w2b : w1b;
    float s = wb[c];
    for (int g = 0; g < DD; g++)
      s += sT[b][g]*w[c*96 + 32 + g] + sWk[b][g]*w[c*96 + 64 + g];
    if (which){ bv2[b*DD+c] = s; sB2[b][c] = s; }
    else      { bv1[b*DD+c] = s; sB1[b][c] = s; }
  }
  __syncthreads();
  {
    int b = tid >> 6, m = tid & 63;
    float s1 = 0.f, s2 = 0.f;
    for (int c = 0; c < DD; c++){
      float p = proj[m*DD + c];
      s1 += sB1[b][c]*p; s2 += sB2[b][c]*p;
    }
    sbd1[b*MM+m] = KSC * s1;
    sbd2[b*MM+m] = KSC * s2;
  }
  if (tid < 16){
    int b = tid & 7;
    float s = 0.f;
    if (tid >> 3){ for (int c = 0; c < DD; c++) s += sB2[b][c]*sB2[b][c]; bc2[b] = 0.5f*KSC2*s; }
    else         { for (int c = 0; c < DD; c++) s += sB1[b][c]*sB1[b][c]; bc1[b] = 0.5f*KSC2*s; }
  }
  if (tid < 256){
    int b = tid >> 5, c = tid & 31;
    float s = inb[c];
    for (int t = 0; t < TT; t++){
      float m0 = xm[(b*TT+t)*2+0], m1 = xm[(b*TT+t)*2+1];
      s += m0 * inw[c*288 + 96 + t] + m1 * inw[c*288 + 192 + t];
    }
    mb[b*DD+c] = s;
  }
}

// ---------------- K1: per-node tables (sd1/sd2/sq/cross + colmax) -----------
__global__ __launch_bounds__(256) void k1_node(
    const float* node_emb, const float* w1w, const float* w2w, const float* proj,
    const float* bv1, const float* bv2,
    float* sd1, float* sd2, float* sq1, float* sq2,
    float* cr1, float* cr2, unsigned* cmx)
{
  __shared__ float sW1[DD][DD], sW2[DD][DD], sP[MM][DD];
  __shared__ float sB1[BB][DD], sB2[BB][DD];
  __shared__ unsigned sCM[MM];
  int tid = threadIdx.x;
  for (int i = tid; i < DD*DD; i += 256){
    int c = i >> 5, g = i & 31;
    sW1[c][g] = w1w[c*96 + g];
    sW2[c][g] = w2w[c*96 + g];
  }
  for (int i = tid; i < MM*DD; i += 256){
    int m = i >> 5, g = i & 31;
    sP[m][g] = proj[i];
  }
  if (tid < BB*DD){
    int b = tid >> 5, c = tid & 31;
    sB1[b][c] = bv1[tid]; sB2[b][c] = bv2[tid];
  }
  if (tid < MM) sCM[tid] = fmapu(-3e38f);
  __syncthreads();
  int n = blockIdx.x*256 + tid;
  bool valid = n < NN;
  int nc = valid ? n : 0;
  float nd[DD];
  #pragma unroll
  for (int g = 0; g < DD; g += 4){
    float4 v = *(const float4*)&node_emb[nc*DD + g];
    nd[g] = v.x; nd[g+1] = v.y; nd[g+2] = v.z; nd[g+3] = v.w;
  }
  float r1[DD], r2[DD];
  #pragma unroll
  for (int c = 0; c < DD; c++){ r1[c] = 0.f; r2[c] = 0.f; }
  #pragma unroll
  for (int g = 0; g < DD; g++){
    float x = nd[g];
    #pragma unroll
    for (int c = 0; c < DD; c++){ r1[c] += x*sW1[c][g]; r2[c] += x*sW2[c][g]; }
  }
  float q1 = 0.f, q2 = 0.f;
  #pragma unroll
  for (int c = 0; c < DD; c++){ q1 += r1[c]*r1[c]; q2 += r2[c]*r2[c]; }
  if (valid){ sq1[n] = 0.5f*KSC2*q1; sq2[n] = 0.5f*KSC2*q2; }
  for (int b = 0; b < BB; b++){
    float c1 = 0.f, c2 = 0.f;
    #pragma unroll
    for (int c = 0; c < DD; c++){ c1 += r1[c]*sB1[b][c]; c2 += r2[c]*sB2[b][c]; }
    if (valid){ cr1[b*NN + n] = KSC2*c1; cr2[b*NN + n] = KSC2*c2; }
  }
  for (int m = 0; m < MM; m++){
    float s1 = 0.f, s2 = 0.f;
    #pragma unroll
    for (int c = 0; c < DD; c++){ float p = sP[m][c]; s1 += r1[c]*p; s2 += r2[c]*p; }
    s1 *= KSC; s2 *= KSC;
    if (valid){
      sd1[(size_t)n*MM + m] = s1;
      sd2[(size_t)n*MM + m] = s2;
      atomicMax(&sCM[m], fmapu(s2));
    }
  }
  __syncthreads();
  if (tid < MM) atomicMax(&cmx[tid], sCM[tid]);
}

// ---------------- K0b: key stabilizer ---------------------------------------
__global__ void k0b_stab(const unsigned* cmx, const float* sbd2, float* stab){
  int lane = threadIdx.x;  // 64
  float cm = funmap(cmx[lane]);
  for (int b = 0; b < BB; b++){
    float v = cm + sbd2[b*MM + lane];
    #pragma unroll
    for (int off = 32; off; off >>= 1) v = fmaxf(v, __shfl_xor(v, off));
    if (lane == 0) stab[b] = v;
  }
}

// ---------------- K2: input embedding -> skip (bf16) ------------------------
__global__ __launch_bounds__(256) void k2_embed(
    const float* x, const float* node_emb, const float* time_tab, const float* week_tab,
    const float* inw, const float* mb, const int* tod, const int* dow,
    u16* skip)
{
  __shared__ float sWt[TT*DD];          // [t][c]
  __shared__ float sMB[DD], sTE[DD], sWE[DD];
  int tid = threadIdx.x;
  int b = blockIdx.y;
  for (int i = tid; i < TT*DD; i += 256){
    int t = i >> 5, c = i & 31;
    sWt[i] = inw[c*288 + t];
  }
  if (tid < DD){
    sMB[tid] = mb[b*DD + tid];
    sTE[tid] = time_tab[tod[b]*DD + tid];
    sWE[tid] = week_tab[dow[b]*DD + tid];
  }
  __syncthreads();
  int n = blockIdx.x*256 + tid;
  bool valid = n < NN;
  int nc = valid ? n : 0;
  float acc[DD];
  #pragma unroll
  for (int c = 0; c < DD; c++) acc[c] = sMB[c];
  const float* xb = x + (size_t)b*TT*NN + nc;
  for (int t = 0; t < TT; t++){
    float xv = xb[(size_t)t*NN];
    #pragma unroll
    for (int c = 0; c < DD; c++) acc[c] += xv * sWt[t*DD + c];
  }
  if (!valid) return;
  float nodev[DD];
  #pragma unroll
  for (int g = 0; g < DD; g += 4){
    float4 v = *(const float4*)&node_emb[n*DD + g];
    nodev[g] = v.x; nodev[g+1] = v.y; nodev[g+2] = v.z; nodev[g+3] = v.w;
  }
  auto chv = [&](int c)->float{
    if (c < 32)  return acc[c];
    if (c < 64)  return nodev[c-32];
    if (c < 96)  return sTE[c-64];
    return sWE[c-96];
  };
  u16* dst = skip + (size_t)(b*NN + n)*CC;
  #pragma unroll
  for (int g = 0; g < CC; g += 8){
    uint4 w;
    w.x = pk2(chv(g+0), chv(g+1));
    w.y = pk2(chv(g+2), chv(g+3));
    w.z = pk2(chv(g+4), chv(g+5));
    w.w = pk2(chv(g+6), chv(g+7));
    *(uint4*)&dst[g] = w;
  }
}

// ---------------- K3: gated projections + kv partial (MFMA) -----------------
__global__ __launch_bounds__(256,1) void k3_gate(
    const u16* hin, const float* inw, const float* outw,
    const float* inb, const float* outb,
    const float* sd2, const float* sq2, const float* cr2,
    const float* sbd2, const float* bc2, const float* stab,
    float* kvp, int layer)
{
  __shared__ u16 sB[256*136];      // weights, [col][k], col = wave*64 + {32 in | 32 out}
  __shared__ u16 sA[64*136];       // h rows bf16, [r][k]
  __shared__ u16 sUT[CC*72];       // gated u, transposed [c][r]
  __shared__ u16 sPhiT[MM*72];     // phi_k transposed [m][r]
  __shared__ float s_inb[CC], s_outb[CC], s_sbd[MM];
  __shared__ float sRed[256];
  int tid = threadIdx.x;
  int b = blockIdx.y, blk = blockIdx.x;
  int lane = tid & 63, wave = tid >> 6, quad = lane >> 4, l15 = lane & 15;

  {
    int j = tid;                         // column 0..255
    int w = j >> 6, jj = j & 63;
    int co = (w << 5) + (jj & 31);
    const float* Wsrc = ((jj & 32) ? outw : inw) + ((size_t)layer*CC + co)*CC;
    for (int ci = 0; ci < CC; ci += 4){
      float4 v = *(const float4*)&Wsrc[ci];
      ushort4 hv4;
      hv4.x = f2bf(v.x); hv4.y = f2bf(v.y); hv4.z = f2bf(v.z); hv4.w = f2bf(v.w);
      *(ushort4*)&sB[j*136 + ci] = hv4;
    }
  }
  if (tid < CC){ s_inb[tid] = inb[layer*CC + tid]; s_outb[tid] = outb[layer*CC + tid]; }
  if (tid < MM) s_sbd[tid] = sbd2[b*MM + tid] - bc2[b] - stab[b];

  f32x4 kvacc[4][2] = {};
  float ksum = 0.f;
  int n_base = blk * ROWS;

  for (int ch = 0; ch < 10; ch++){
    int n0 = n_base + ch*64;
    __syncthreads();
    { // stage A: 64 rows x 128 (bf16 direct copy)
      int r = tid >> 2, cs = (tid & 3) * 32;
      int n = n0 + r;
      bool v = n < NN;
      const u16* src = hin + (size_t)(b*NN + min(n, NN-1))*CC + cs;
      #pragma unroll
      for (int k = 0; k < 4; k++){
        uint4 d = {0,0,0,0};
        if (v) d = *(const uint4*)&src[k*8];
        *(uint4*)&sA[r*136 + cs + k*8] = d;
      }
    }
    { // stage phi_k^T
      int m = tid & 63, rg = tid >> 6;
      #pragma unroll
      for (int s = 0; s < 16; s++){
        int r = rg*16 + s;
        int n = n0 + r;
        bool v = n < NN;
        int nc2 = v ? n : 0;
        float dv = sd2[(size_t)nc2*MM + m];
        float e = dv + s_sbd[m] - sq2[nc2] - cr2[b*NN + nc2];
        float pv = v ? (0.125f*__expf(e) + 0.125e-6f) : 0.f;
        u16 pb = f2bf(pv);
        sPhiT[m*72 + r] = pb;
        ksum += bf2f(pb);
      }
    }
    __syncthreads();
    // gate GEMM: u_pre/v_pre = h @ [in_w|out_w]^T
    f32x4 acc[4][4] = {};
    #pragma unroll
    for (int ks = 0; ks < 4; ks++){
      int k0 = ks*32 + quad*8;
      bf16x8 af[4], bf[4];
      #pragma unroll
      for (int mt = 0; mt < 4; mt++) af[mt] = *(const bf16x8*)&sA[(mt*16+l15)*136 + k0];
      #pragma unroll
      for (int nt = 0; nt < 4; nt++) bf[nt] = *(const bf16x8*)&sB[(wave*64+nt*16+l15)*136 + k0];
      #pragma unroll
      for (int mt = 0; mt < 4; mt++)
        #pragma unroll
        for (int nt = 0; nt < 4; nt++)
          acc[mt][nt] = __builtin_amdgcn_mfma_f32_16x16x32_bf16(af[mt], bf[nt], acc[mt][nt], 0, 0, 0);
    }
    // gating -> sUT (transposed [c][r])
    #pragma unroll
    for (int mt = 0; mt < 4; mt++){
      int r0 = mt*16 + quad*4;
      #pragma unroll
      for (int nt = 0; nt < 2; nt++){
        int co = wave*32 + nt*16 + l15;
        float bi = s_inb[co], bo = s_outb[co];
        float uv[4];
        #pragma unroll
        for (int e = 0; e < 4; e++){
          float up = acc[mt][nt][e] + bi;
          float vp = acc[mt][nt+2][e] + bo;
          float u = vp / (1.f + __expf(-up));
          if (n0 + r0 + e >= NN) u = 0.f;
          uv[e] = u;
        }
        ushort4 hv4;
        hv4.x = f2bf(uv[0]); hv4.y = f2bf(uv[1]); hv4.z = f2bf(uv[2]); hv4.w = f2bf(uv[3]);
        *(ushort4*)&sUT[co*72 + r0] = hv4;
      }
    }
    __syncthreads();
    // kv GEMM: kv[m][c] += phi_k^T @ u  (K = 64 rows)
    #pragma unroll
    for (int ks = 0; ks < 2; ks++){
      int k0 = ks*32 + quad*8;
      bf16x8 ap[4], bu[2];
      #pragma unroll
      for (int mt = 0; mt < 4; mt++) ap[mt] = *(const bf16x8*)&sPhiT[(mt*16+l15)*72 + k0];
      #pragma unroll
      for (int nt = 0; nt < 2; nt++) bu[nt] = *(const bf16x8*)&sUT[(wave*32+nt*16+l15)*72 + k0];
      #pragma unroll
      for (int mt = 0; mt < 4; mt++)
        #pragma unroll
        for (int nt = 0; nt < 2; nt++)
          kvacc[mt][nt] = __builtin_amdgcn_mfma_f32_16x16x32_bf16(ap[mt], bu[nt], kvacc[mt][nt], 0, 0, 0);
    }
  }
  float* myp = kvp + (size_t)(b*NBLK + blk)*MM*KV_PITCH;
  #pragma unroll
  for (int mt = 0; mt < 4; mt++)
    #pragma unroll
    for (int nt = 0; nt < 2; nt++)
      #pragma unroll
      for (int e = 0; e < 4; e++){
        int m = mt*16 + quad*4 + e;
        int c = wave*32 + nt*16 + l15;
        myp[m*KV_PITCH + c] = kvacc[mt][nt][e];
      }
  sRed[tid] = ksum;
  __syncthreads();
  if (tid < MM){
    float s = sRed[tid] + sRed[tid+64] + sRed[tid+128] + sRed[tid+192];
    myp[tid*KV_PITCH + 128] = s;
  }
}

// ---------------- K4: reduce kv partials ------------------------------------
__global__ void k4_reduce(const float* kvp, u16* kvt, float* ksumf){
  int m = blockIdx.x, b = blockIdx.y;
  int c = threadIdx.x;  // 128
  float s = 0.f;
  for (int blk = 0; blk < NBLK; blk++)
    s += kvp[(size_t)((b*NBLK+blk)*MM + m)*KV_PITCH + c];
  kvt[(size_t)(b*CC + c)*MM + m] = f2bf(s);
  if (c == 0){
    float t = 0.f;
    for (int blk = 0; blk < NBLK; blk++)
      t += kvp[(size_t)((b*NBLK+blk)*MM + m)*KV_PITCH + 128];
    ksumf[b*MM + m] = t;
  }
}

// ---------------- K5: num/den + residual + LayerNorm (MFMA) -----------------
__global__ __launch_bounds__(256,2) void k5_attn(
    const u16* hin, u16* hout,
    const float* sd1, const float* sq1, const float* cr1,
    const float* sbd1, const float* bc1,
    const u16* kvt, const float* ksumf,
    const float* lng, const float* lnb, int layer)
{
  __shared__ u16 sPq[MM*72];       // phi_q [r][m]
  __shared__ u16 sKv[CC*72];       // kv^T  [c][m]
  __shared__ float sY[64*132];     // residual/accumulated rows
  __shared__ float sDen[64], sKs[MM], sSbd[MM];
  __shared__ float sMu[64], sRs[64];
  __shared__ float sLg[CC], sLb[CC];
  __shared__ float sRed[512];
  int tid = threadIdx.x;
  int b = blockIdx.y, blk = blockIdx.x;
  int lane = tid & 63, wave = tid >> 6, quad = lane >> 4, l15 = lane & 15;
  {
    int c = tid >> 1, mh = (tid & 1)*32;
    const u16* src = kvt + (size_t)(b*CC + c)*MM + mh;
    #pragma unroll
    for (int k = 0; k < 4; k++)
      *(uint4*)&sKv[c*72 + mh + k*8] = *(const uint4*)&src[k*8];
  }
  if (tid < MM){ sKs[tid] = ksumf[b*MM+tid]; sSbd[tid] = sbd1[b*MM+tid]; }
  if (tid < CC){ sLg[tid] = lng[layer*CC+tid]; sLb[tid] = lnb[layer*CC+tid]; }
  float bc = bc1[b];
  int n_base = blk * ROWS;
  for (int ch = 0; ch < 10; ch++){
    int n0 = n_base + ch*64;
    __syncthreads();
    { // stage residual rows (bf16 -> f32)
      int r = tid >> 2, cs = (tid & 3)*32;
      int n = n0 + r;
      bool v = n < NN;
      const u16* src = hin + (size_t)(b*NN + min(n, NN-1))*CC + cs;
      #pragma unroll
      for (int k = 0; k < 32; k += 8){
        uint4 d = {0,0,0,0};
        if (v) d = *(const uint4*)&src[k];
        float4 f0 = { __uint_as_float(d.x<<16), __uint_as_float(d.x & 0xffff0000u),
                      __uint_as_float(d.y<<16), __uint_as_float(d.y & 0xffff0000u) };
        float4 f1 = { __uint_as_float(d.z<<16), __uint_as_float(d.z & 0xffff0000u),
                      __uint_as_float(d.w<<16), __uint_as_float(d.w & 0xffff0000u) };
        *(float4*)&sY[r*132 + cs + k]     = f0;
        *(float4*)&sY[r*132 + cs + k + 4] = f1;
      }
    }
    { // phi_q + den; wave w handles rows w*16 .. w*16+15, lane = m
      #pragma unroll
      for (int s = 0; s < 16; s++){
        int r = wave*16 + s;
        int n = n0 + r;
        bool v = n < NN;
        int nc2 = v ? n : 0;
        float dashv = sd1[(size_t)nc2*MM + lane] + sSbd[lane];
        float rm = dashv;
        #pragma unroll
        for (int off = 32; off; off >>= 1) rm = fmaxf(rm, __shfl_xor(rm, off));
        float diagv = sq1[nc2] + cr1[b*NN + nc2] + bc;
        float pv = v ? (0.125f*__expf(dashv - rm - diagv) + 0.125e-6f) : 0.f;
        u16 pb = f2bf(pv);
        sPq[r*72 + lane] = pb;
        float dp = bf2f(pb) * sKs[lane];
        #pragma unroll
        for (int off = 32; off; off >>= 1) dp += __shfl_xor(dp, off);
        if (lane == 0) sDen[r] = dp;
      }
    }
    __syncthreads();
    f32x4 nacc[4][2] = {};
    #pragma unroll
    for (int ks = 0; ks < 2; ks++){
      int k0 = ks*32 + quad*8;
      bf16x8 ap[4], bk[2];
      #pragma unroll
      for (int mt = 0; mt < 4; mt++) ap[mt] = *(const bf16x8*)&sPq[(mt*16+l15)*72 + k0];
      #pragma unroll
      for (int nt = 0; nt < 2; nt++) bk[nt] = *(const bf16x8*)&sKv[(wave*32+nt*16+l15)*72 + k0];
      #pragma unroll
      for (int mt = 0; mt < 4; mt++)
        #pragma unroll
        for (int nt = 0; nt < 2; nt++)
          nacc[mt][nt] = __builtin_amdgcn_mfma_f32_16x16x32_bf16(ap[mt], bk[nt], nacc[mt][nt], 0, 0, 0);
    }
    // y = num/den + res
    #pragma unroll
    for (int mt = 0; mt < 4; mt++)
      #pragma unroll
      for (int nt = 0; nt < 2; nt++){
        int c = wave*32 + nt*16 + l15;
        #pragma unroll
        for (int e = 0; e < 4; e++){
          int r = mt*16 + quad*4 + e;
          sY[r*132 + c] = nacc[mt][nt][e]/sDen[r] + sY[r*132 + c];
        }
      }
    __syncthreads();
    { // LN stats
      int r = tid >> 2, q = tid & 3;
      float s1 = 0.f, s2 = 0.f;
      #pragma unroll
      for (int k = 0; k < 32; k++){
        float y = sY[r*132 + q*32 + k];
        s1 += y; s2 += y*y;
      }
      sRed[tid] = s1; sRed[256 + tid] = s2;
    }
    __syncthreads();
    if ((tid & 3) == 0){
      int r = tid >> 2;
      float s1 = sRed[tid] + sRed[tid+1] + sRed[tid+2] + sRed[tid+3];
      float s2 = sRed[256+tid] + sRed[256+tid+1] + sRed[256+tid+2] + sRed[256+tid+3];
      float mu = s1 * (1.f/CC);
      float var = s2 * (1.f/CC) - mu*mu;
      sMu[r] = mu; sRs[r] = rsqrtf(var + 1e-5f);
    }
    __syncthreads();
    { // normalize + write bf16
      int r = tid >> 2, cs = (tid & 3)*32;
      int n = n0 + r;
      if (n < NN){
        float mu = sMu[r], rs = sRs[r];
        u16* dst = hout + (size_t)(b*NN + n)*CC + cs;
        #pragma unroll
        for (int k = 0; k < 32; k += 8){
          float v0 = (sY[r*132+cs+k+0]-mu)*rs*sLg[cs+k+0] + sLb[cs+k+0];
          float v1 = (sY[r*132+cs+k+1]-mu)*rs*sLg[cs+k+1] + sLb[cs+k+1];
          float v2 = (sY[r*132+cs+k+2]-mu)*rs*sLg[cs+k+2] + sLb[cs+k+2];
          float v3 = (sY[r*132+cs+k+3]-mu)*rs*sLg[cs+k+3] + sLb[cs+k+3];
          float v4 = (sY[r*132+cs+k+4]-mu)*rs*sLg[cs+k+4] + sLb[cs+k+4];
          float v5 = (sY[r*132+cs+k+5]-mu)*rs*sLg[cs+k+5] + sLb[cs+k+5];
          float v6 = (sY[r*132+cs+k+6]-mu)*rs*sLg[cs+k+6] + sLb[cs+k+6];
          float v7 = (sY[r*132+cs+k+7]-mu)*rs*sLg[cs+k+7] + sLb[cs+k+7];
          uint4 wv = { pk2(v0,v1), pk2(v2,v3), pk2(v4,v5), pk2(v6,v7) };
          *(uint4*)&dst[k] = wv;
        }
      }
    }
  }
}

// ---------------- K6: regression head + transpose ---------------------------
__global__ __launch_bounds__(256) void k6_final(
    const u16* skip, const u16* hbuf, const float* regw, const float* regb,
    float* out)
{
  __shared__ float sRW[PP*256];
  __shared__ float sRB[PP];
  int tid = threadIdx.x;
  for (int i = tid; i < PP*256; i += 256) sRW[i] = regw[i];
  if (tid < PP) sRB[tid] = regb[tid];
  __syncthreads();
  int b = blockIdx.y;
  int n = blockIdx.x*256 + tid;
  if (n >= NN) return;
  float acc[PP];
  #pragma unroll
  for (int p = 0; p < PP; p++) acc[p] = sRB[p];
  const u16* sr = skip + (size_t)(b*NN + n)*CC;
  const u16* hr = hbuf + (size_t)(b*NN + n)*CC;
  for (int half = 0; half < 2; half++){
    const u16* src = half ? hr : sr;
    int coff = half*128;
    for (int k = 0; k < CC; k += 8){
      uint4 d = *(const uint4*)&src[k];
      float v0 = __uint_as_float(d.x<<16), v1 = __uint_as_float(d.x & 0xffff0000u);
      float v2 = __uint_as_float(d.y<<16), v3 = __uint_as_float(d.y & 0xffff0000u);
      float v4 = __uint_as_float(d.z<<16), v5 = __uint_as_float(d.z & 0xffff0000u);
      float v6 = __uint_as_float(d.w<<16), v7 = __uint_as_float(d.w & 0xffff0000u);
      #pragma unroll
      for (int p = 0; p < PP; p++){
        const float* wr = &sRW[p*256 + coff + k];
        acc[p] += v0*wr[0] + v1*wr[1] + v2*wr[2] + v3*wr[3]
                + v4*wr[4] + v5*wr[5] + v6*wr[6] + v7*wr[7];
      }
    }
  }
  #pragma unroll
  for (int p = 0; p < PP; p++)
    out[(size_t)(b*PP + p)*NN + n] = acc[p];
}

// ---------------- launcher ---------------------------------------------------
extern "C" void kernel_launch(void* const* d_in, const int* in_sizes, int n_in,
                              void* d_out, int out_size, void* d_ws, size_t ws_size,
                              hipStream_t stream)
{
  const float* x        = (const float*)d_in[0];
  const float* xm       = (const float*)d_in[1];
  const float* node_emb = (const float*)d_in[2];
  const float* time_tab = (const float*)d_in[3];
  const float* week_tab = (const float*)d_in[4];
  const float* input_w  = (const float*)d_in[5];
  // d_in[6] = input_b (folded into markbias via k0)
  const float* input_b  = (const float*)d_in[6];
  const float* w1w      = (const float*)d_in[7];
  const float* w1b      = (const float*)d_in[8];
  const float* w2w      = (const float*)d_in[9];
  const float* w2b      = (const float*)d_in[10];
  const float* inw      = (const float*)d_in[11];
  const float* inb      = (const float*)d_in[12];
  const float* outw     = (const float*)d_in[13];
  const float* outb     = (const float*)d_in[14];
  const float* lng      = (const float*)d_in[15];
  const float* lnb      = (const float*)d_in[16];
  const float* regw     = (const float*)d_in[17];
  const float* regb     = (const float*)d_in[18];
  const float* proj     = (const float*)d_in[19];
  float* out = (float*)d_out;

  char* wsb = (char*)d_ws;
  size_t off = 0;
  auto alloc = [&](size_t bytes)->char*{
    char* p = wsb + off; off += (bytes + 255) & ~(size_t)255; return p;
  };
  u16*   skip  = (u16*)  alloc((size_t)BB*NN*CC*2);
  u16*   hbuf  = (u16*)  alloc((size_t)BB*NN*CC*2);
  float* sd1   = (float*)alloc((size_t)NN*MM*4);
  float* sd2   = (float*)alloc((size_t)NN*MM*4);
  float* sq1   = (float*)alloc((size_t)NN*4);
  float* sq2   = (float*)alloc((size_t)NN*4);
  float* cr1   = (float*)alloc((size_t)BB*NN*4);
  float* cr2   = (float*)alloc((size_t)BB*NN*4);
  float* bv1   = (float*)alloc(BB*DD*4);
  float* bv2   = (float*)alloc(BB*DD*4);
  float* sbd1  = (float*)alloc(BB*MM*4);
  float* sbd2  = (float*)alloc(BB*MM*4);
  float* bc1   = (float*)alloc(BB*4);
  float* bc2   = (float*)alloc(BB*4);
  float* mb    = (float*)alloc(BB*DD*4);
  int*   tod   = (int*)  alloc(BB*4);
  int*   dow   = (int*)  alloc(BB*4);
  unsigned* cmx= (unsigned*)alloc(MM*4);
  float* stab  = (float*)alloc(BB*4);
  float* ksumf = (float*)alloc(BB*MM*4);
  float* kvp   = (float*)alloc((size_t)BB*NBLK*MM*KV_PITCH*4);
  u16*   kvt   = (u16*)  alloc((size_t)BB*CC*MM*2);
  (void)ws_size; (void)in_sizes; (void)n_in; (void)out_size;

  k0_prep<<<1, 512, 0, stream>>>(xm, time_tab, week_tab, w1w, w1b, w2w, w2b,
                                 input_w, input_b, proj,
                                 bv1, bv2, sbd1, sbd2, bc1, bc2, mb, tod, dow, cmx);
  k1_node<<<79, 256, 0, stream>>>(node_emb, w1w, w2w, proj, bv1, bv2,
                                  sd1, sd2, sq1, sq2, cr1, cr2, cmx);
  k0b_stab<<<1, 64, 0, stream>>>(cmx, sbd2, stab);
  k2_embed<<<dim3(79, 8), 256, 0, stream>>>(x, node_emb, time_tab, week_tab,
                                            input_w, mb, tod, dow, skip);
  for (int l = 0; l < LL; l++){
    const u16* hi = (l == 0) ? skip : hbuf;
    k3_gate<<<dim3(NBLK, 8), 256, 0, stream>>>(hi, inw, outw, inb, outb,
                                               sd2, sq2, cr2, sbd2, bc2, stab, kvp, l);
    k4_reduce<<<dim3(64, 8), 128, 0, stream>>>(kvp, kvt, ksumf);
    k5_attn<<<dim3(NBLK, 8), 256, 0, stream>>>(hi, hbuf, sd1, sq1, cr1, sbd1, bc1,
                                               kvt, ksumf, lng, lnb, l);
  }
  k6_final<<<dim3(79, 8), 256, 0, stream>>>(skip, hbuf, regw, regb, out);
}

// Round 2
// 803.102 us; speedup vs baseline: 1.4856x; 1.4856x over previous
//
#include <hip/hip_runtime.h>

typedef unsigned short u16;
typedef __attribute__((ext_vector_type(8))) __bf16 bf16x8;
typedef __attribute__((ext_vector_type(4))) float f32x4;

#define BB 8
#define TT 96
#define NN 20000
#define NP 20160          // padded n for phi_k^T (k3 reads up to 105*192=20160)
#define PP 12
#define LL 3
#define DD 32
#define CC 128
#define MM 64
#define NB3 105           // k3 blocks per batch (3 chunks of 64 rows each)
#define NB5 313           // k5 blocks per batch (1 chunk of 64 rows)

constexpr float KSC  = 0.8408964152537145f;   // 2 * 32^-0.25
constexpr float KSC2 = 0.7071067811865476f;   // KSC^2

__device__ inline u16 f2bf(float f){
  unsigned u = __float_as_uint(f);
  u = (u + 0x7fffu + ((u >> 16) & 1u)) >> 16;
  return (u16)u;
}
__device__ inline float bf2f(u16 h){ return __uint_as_float(((unsigned)h) << 16); }
__device__ inline unsigned fmapu(float f){
  unsigned u = __float_as_uint(f);
  return (u & 0x80000000u) ? ~u : (u | 0x80000000u);
}
__device__ inline float funmap(unsigned u){
  return (u & 0x80000000u) ? __uint_as_float(u & 0x7fffffffu) : __uint_as_float(~u);
}
__device__ inline unsigned pk2(float a, float b){
  return (unsigned)f2bf(a) | ((unsigned)f2bf(b) << 16);
}

// ---------------- K0: per-batch scalars + ksum zero -------------------------
__global__ void k0_prep(const float* xm, const float* time_tab, const float* week_tab,
                        const float* w1w, const float* w1b, const float* w2w, const float* w2b,
                        const float* inw, const float* inb, const float* proj,
                        float* bv1, float* bv2, float* sbd1, float* sbd2,
                        float* bc1, float* bc2, float* mb, int* tod, int* dow,
                        unsigned* cmx, float* ksum)
{
  __shared__ float sT[BB][DD], sWk[BB][DD];
  __shared__ float sB1[BB][DD], sB2[BB][DD];
  __shared__ int sTod[BB], sDow[BB];
  int tid = threadIdx.x;  // 512
  ksum[tid] = 0.f;        // 8*64 == 512
  if (tid < BB){
    float t0 = xm[(tid*TT + TT-1)*2 + 0];
    float t1 = xm[(tid*TT + TT-1)*2 + 1];
    int ti = (int)(t0 * (float)TT); ti = min(max(ti, 0), TT-1);
    int di = (int)(t1 * 7.0f);      di = min(max(di, 0), 6);
    sTod[tid] = ti; sDow[tid] = di; tod[tid] = ti; dow[tid] = di;
  }
  if (tid < MM) cmx[tid] = fmapu(-3e38f);
  __syncthreads();
  if (tid < BB*DD){
    int b = tid >> 5, g = tid & 31;
    sT[b][g]  = time_tab[sTod[b]*DD + g];
    sWk[b][g] = week_tab[sDow[b]*DD + g];
  }
  __syncthreads();
  {
    int which = tid >> 8, b = (tid >> 5) & 7, c = tid & 31;
    const float* w  = which ? w2w : w1w;
    const float* wb = which ? w2b : w1b;
    float s = wb[c];
    for (int g = 0; g < DD; g++)
      s += sT[b][g]*w[c*96 + 32 + g] + sWk[b][g]*w[c*96 + 64 + g];
    if (which){ bv2[b*DD+c] = s; sB2[b][c] = s; }
    else      { bv1[b*DD+c] = s; sB1[b][c] = s; }
  }
  __syncthreads();
  {
    int b = tid >> 6, m = tid & 63;
    float s1 = 0.f, s2 = 0.f;
    for (int c = 0; c < DD; c++){
      float p = proj[m*DD + c];
      s1 += sB1[b][c]*p; s2 += sB2[b][c]*p;
    }
    sbd1[b*MM+m] = KSC * s1;
    sbd2[b*MM+m] = KSC * s2;
  }
  if (tid < 16){
    int b = tid & 7;
    float s = 0.f;
    if (tid >> 3){ for (int c = 0; c < DD; c++) s += sB2[b][c]*sB2[b][c]; bc2[b] = 0.5f*KSC2*s; }
    else         { for (int c = 0; c < DD; c++) s += sB1[b][c]*sB1[b][c]; bc1[b] = 0.5f*KSC2*s; }
  }
  if (tid < 256){
    int b = tid >> 5, c = tid & 31;
    float s = inb[c];
    for (int t = 0; t < TT; t++){
      float m0 = xm[(b*TT+t)*2+0], m1 = xm[(b*TT+t)*2+1];
      s += m0 * inw[c*288 + 96 + t] + m1 * inw[c*288 + 192 + t];
    }
    mb[b*DD+c] = s;
  }
}

// ---------------- K1: per-node tables + weight bf16 cast + kv zero ----------
__global__ __launch_bounds__(256) void k1_node(
    const float* node_emb, const float* w1w, const float* w2w, const float* proj,
    const float* bv1, const float* bv2,
    const float* gin_w, const float* gout_w,
    float* sd1, float* sd2, float* sq1, float* sq2,
    float* cr1, float* cr2, unsigned* cmx,
    u16* wbf, float* kvz)
{
  __shared__ float sW1[DD][DD], sW2[DD][DD], sP[MM][DD];
  __shared__ float sB1[BB][DD], sB2[BB][DD];
  __shared__ unsigned sCM[MM];
  int tid = threadIdx.x;
  int gid = blockIdx.x*256 + tid;
  // zero the 3 per-layer kv accumulators (atomic targets)
  for (int i = gid; i < LL*BB*MM*CC; i += 79*256) kvz[i] = 0.f;
  // cast gate weights to bf16: wbf[which][layer][co][ci]
  for (int i = gid; i < 2*LL*CC*CC; i += 79*256){
    int which = i / (LL*CC*CC);
    int r = i - which*(LL*CC*CC);
    wbf[i] = f2bf((which ? gout_w : gin_w)[r]);
  }
  for (int i = tid; i < DD*DD; i += 256){
    int c = i >> 5, g = i & 31;
    sW1[c][g] = w1w[c*96 + g];
    sW2[c][g] = w2w[c*96 + g];
  }
  for (int i = tid; i < MM*DD; i += 256) sP[i >> 5][i & 31] = proj[i];
  if (tid < BB*DD){
    int b = tid >> 5, c = tid & 31;
    sB1[b][c] = bv1[tid]; sB2[b][c] = bv2[tid];
  }
  if (tid < MM) sCM[tid] = fmapu(-3e38f);
  __syncthreads();
  int n = blockIdx.x*256 + tid;
  bool valid = n < NN;
  int nc = valid ? n : 0;
  float nd[DD];
  #pragma unroll
  for (int g = 0; g < DD; g += 4){
    float4 v = *(const float4*)&node_emb[nc*DD + g];
    nd[g] = v.x; nd[g+1] = v.y; nd[g+2] = v.z; nd[g+3] = v.w;
  }
  float r1[DD], r2[DD];
  #pragma unroll
  for (int c = 0; c < DD; c++){ r1[c] = 0.f; r2[c] = 0.f; }
  #pragma unroll
  for (int g = 0; g < DD; g++){
    float x = nd[g];
    #pragma unroll
    for (int c = 0; c < DD; c++){ r1[c] += x*sW1[c][g]; r2[c] += x*sW2[c][g]; }
  }
  float q1 = 0.f, q2 = 0.f;
  #pragma unroll
  for (int c = 0; c < DD; c++){ q1 += r1[c]*r1[c]; q2 += r2[c]*r2[c]; }
  if (valid){ sq1[n] = 0.5f*KSC2*q1; sq2[n] = 0.5f*KSC2*q2; }
  for (int b = 0; b < BB; b++){
    float c1 = 0.f, c2 = 0.f;
    #pragma unroll
    for (int c = 0; c < DD; c++){ c1 += r1[c]*sB1[b][c]; c2 += r2[c]*sB2[b][c]; }
    if (valid){ cr1[b*NN + n] = KSC2*c1; cr2[b*NN + n] = KSC2*c2; }
  }
  for (int m = 0; m < MM; m++){
    float s1 = 0.f, s2 = 0.f;
    #pragma unroll
    for (int c = 0; c < DD; c++){ float p = sP[m][c]; s1 += r1[c]*p; s2 += r2[c]*p; }
    s1 *= KSC; s2 *= KSC;
    if (valid){
      sd1[(size_t)n*MM + m] = s1;
      sd2[(size_t)n*MM + m] = s2;
      atomicMax(&sCM[m], fmapu(s2));
    }
  }
  __syncthreads();
  if (tid < MM) atomicMax(&cmx[tid], sCM[tid]);
}

// ---------------- K0b: key stabilizer ---------------------------------------
__global__ void k0b_stab(const unsigned* cmx, const float* sbd2, float* stab){
  int lane = threadIdx.x;  // 64
  float cm = funmap(cmx[lane]);
  for (int b = 0; b < BB; b++){
    float v = cm + sbd2[b*MM + lane];
    #pragma unroll
    for (int off = 32; off; off >>= 1) v = fmaxf(v, __shfl_xor(v, off));
    if (lane == 0) stab[b] = v;
  }
}

// ---------------- K1b: materialize phi_q [b][n][m], phi_k^T [b][m][NP], ksum
__global__ __launch_bounds__(256) void k1b_phi(
    const float* sd1, const float* sd2, const float* sq1, const float* sq2,
    const float* cr1, const float* cr2, const float* sbd1, const float* sbd2,
    const float* bc1, const float* bc2, const float* stab,
    u16* phiq, u16* phikt, float* ksum)
{
  __shared__ u16 sT[MM][264];     // phi_k^T tile [m][r], 256 rows + pad
  __shared__ float sQb[MM], sKb[MM];
  __shared__ float sRed[256];
  int tid = threadIdx.x;
  int b = blockIdx.y, n0 = blockIdx.x*256;
  if (tid < MM){
    sQb[tid] = sbd1[b*MM + tid];
    sKb[tid] = sbd2[b*MM + tid] - bc2[b] - stab[b];
  }
  __syncthreads();
  int n = n0 + tid;
  bool v = n < NN;
  int nc = v ? n : 0;
  float dq[MM];
  const float* s1r = sd1 + (size_t)nc*MM;
  #pragma unroll
  for (int m = 0; m < MM; m += 4){
    float4 t = *(const float4*)&s1r[m];
    dq[m]=t.x; dq[m+1]=t.y; dq[m+2]=t.z; dq[m+3]=t.w;
  }
  float rm = -3e38f;
  #pragma unroll
  for (int m = 0; m < MM; m++) rm = fmaxf(rm, dq[m] + sQb[m]);
  float diagq = sq1[nc] + cr1[b*NN + nc] + bc1[b];
  u16* pqr = phiq + ((size_t)(b*NN) + nc)*MM;
  #pragma unroll
  for (int m = 0; m < MM; m += 8){
    float p[8];
    #pragma unroll
    for (int j = 0; j < 8; j++){
      float ev = dq[m+j] + sQb[m+j] - rm - diagq;
      p[j] = 0.125f*__expf(ev) + 1.25e-7f;
    }
    uint4 w = { pk2(p[0],p[1]), pk2(p[2],p[3]), pk2(p[4],p[5]), pk2(p[6],p[7]) };
    if (v) *(uint4*)&pqr[m] = w;
  }
  // phi_k -> transposed LDS tile (zero for padded rows)
  const float* s2r = sd2 + (size_t)nc*MM;
  float diagk = sq2[nc] + cr2[b*NN + nc];
  #pragma unroll
  for (int m = 0; m < MM; m++){
    float ev = s2r[m] + sKb[m] - diagk;
    float pv = v ? (0.125f*__expf(ev) + 1.25e-7f) : 0.f;
    sT[m][tid] = f2bf(pv);
  }
  __syncthreads();
  {
    int m = tid >> 2, q = tid & 3;
    float s = 0.f;
    for (int j = 0; j < 64; j++) s += bf2f(sT[m][q*64 + j]);
    sRed[tid] = s;
  }
  __syncthreads();
  if (tid < MM){
    float s = sRed[tid*4] + sRed[tid*4+1] + sRed[tid*4+2] + sRed[tid*4+3];
    atomicAdd(&ksum[b*MM + tid], s);
  }
  {
    int m = tid >> 2, q = tid & 3;
    int nb = n0 + q*64;
    if (nb + 64 <= NP){
      u16* dst = phikt + (size_t)(b*MM + m)*NP + nb;
      #pragma unroll
      for (int j = 0; j < 64; j += 8)
        *(uint4*)&dst[j] = *(const uint4*)&sT[m][q*64 + j];
    }
  }
}

// ---------------- K2: input embedding -> skip (bf16) ------------------------
__global__ __launch_bounds__(256) void k2_embed(
    const float* x, const float* node_emb, const float* time_tab, const float* week_tab,
    const float* inw, const float* mb, const int* tod, const int* dow,
    u16* skip)
{
  __shared__ float sWt[TT*DD];          // [t][c]
  __shared__ float sMB[DD], sTE[DD], sWE[DD];
  int tid = threadIdx.x;
  int b = blockIdx.y;
  for (int i = tid; i < TT*DD; i += 256){
    int t = i >> 5, c = i & 31;
    sWt[i] = inw[c*288 + t];
  }
  if (tid < DD){
    sMB[tid] = mb[b*DD + tid];
    sTE[tid] = time_tab[tod[b]*DD + tid];
    sWE[tid] = week_tab[dow[b]*DD + tid];
  }
  __syncthreads();
  int n = blockIdx.x*256 + tid;
  bool valid = n < NN;
  int nc = valid ? n : 0;
  float acc[DD];
  #pragma unroll
  for (int c = 0; c < DD; c++) acc[c] = sMB[c];
  const float* xb = x + (size_t)b*TT*NN + nc;
  for (int t = 0; t < TT; t++){
    float xv = xb[(size_t)t*NN];
    #pragma unroll
    for (int c = 0; c < DD; c++) acc[c] += xv * sWt[t*DD + c];
  }
  if (!valid) return;
  float nodev[DD];
  #pragma unroll
  for (int g = 0; g < DD; g += 4){
    float4 v = *(const float4*)&node_emb[n*DD + g];
    nodev[g] = v.x; nodev[g+1] = v.y; nodev[g+2] = v.z; nodev[g+3] = v.w;
  }
  auto chv = [&](int c)->float{
    if (c < 32)  return acc[c];
    if (c < 64)  return nodev[c-32];
    if (c < 96)  return sTE[c-64];
    return sWE[c-96];
  };
  u16* dst = skip + (size_t)(b*NN + n)*CC;
  #pragma unroll
  for (int g = 0; g < CC; g += 8){
    uint4 w;
    w.x = pk2(chv(g+0), chv(g+1));
    w.y = pk2(chv(g+2), chv(g+3));
    w.z = pk2(chv(g+4), chv(g+5));
    w.w = pk2(chv(g+6), chv(g+7));
    *(uint4*)&dst[g] = w;
  }
}

// ---------------- K3: gated projections + kv atomic accumulate (MFMA) -------
__global__ __launch_bounds__(256,2) void k3_gate(
    const u16* hin, const u16* wbf, const float* inb, const float* outb,
    const u16* phikt, float* kv, int layer)
{
  __shared__ u16 sUT[CC*72];       // gated u, transposed [c][r]
  __shared__ float s_inb[CC], s_outb[CC];
  int tid = threadIdx.x;
  int b = blockIdx.y, blk = blockIdx.x;
  int lane = tid & 63, wave = tid >> 6, quad = lane >> 4, l15 = lane & 15;
  if (tid < CC){ s_inb[tid] = inb[layer*CC + tid]; s_outb[tid] = outb[layer*CC + tid]; }

  // per-wave weight B-fragments in registers: bw[ks][nt]
  bf16x8 bw[4][4];
  #pragma unroll
  for (int nt = 0; nt < 4; nt++){
    int which = nt >> 1;
    int co = wave*32 + (nt & 1)*16 + l15;
    const u16* wp = wbf + ((size_t)(which*LL + layer)*CC + co)*CC;
    #pragma unroll
    for (int ks = 0; ks < 4; ks++)
      bw[ks][nt] = *(const bf16x8*)&wp[ks*32 + quad*8];
  }
  f32x4 kvacc[4][2] = {};
  const u16* hbase = hin + (size_t)(b*NN)*CC;

  for (int ch = 0; ch < 3; ch++){
    int n0 = blk*192 + ch*64;
    // gate GEMM: A from global (row-major == A-frag layout), B in regs
    f32x4 acc[4][4] = {};
    bf16x8 af[2][4];
    #pragma unroll
    for (int mt = 0; mt < 4; mt++)
      af[0][mt] = *(const bf16x8*)&hbase[(size_t)(n0 + mt*16 + l15)*CC + quad*8];
    #pragma unroll
    for (int ks = 0; ks < 4; ks++){
      int cur = ks & 1, nxt = cur ^ 1;
      if (ks < 3){
        #pragma unroll
        for (int mt = 0; mt < 4; mt++)
          af[nxt][mt] = *(const bf16x8*)&hbase[(size_t)(n0 + mt*16 + l15)*CC + (ks+1)*32 + quad*8];
      }
      #pragma unroll
      for (int mt = 0; mt < 4; mt++)
        #pragma unroll
        for (int nt = 0; nt < 4; nt++)
          acc[mt][nt] = __builtin_amdgcn_mfma_f32_16x16x32_bf16(af[cur][mt], bw[ks][nt], acc[mt][nt], 0, 0, 0);
    }
    __syncthreads();   // previous chunk's sUT fully consumed
    // gating -> sUT (transposed [c][r])
    #pragma unroll
    for (int mt = 0; mt < 4; mt++){
      int r0 = mt*16 + quad*4;
      #pragma unroll
      for (int nt = 0; nt < 2; nt++){
        int co = wave*32 + nt*16 + l15;
        float bi = s_inb[co], bo = s_outb[co];
        float uv[4];
        #pragma unroll
        for (int e = 0; e < 4; e++){
          float up = acc[mt][nt][e] + bi;
          float vp = acc[mt][nt+2][e] + bo;
          float u = vp / (1.f + __expf(-up));
          if (n0 + r0 + e >= NN) u = 0.f;
          uv[e] = u;
        }
        ushort4 hv4;
        hv4.x = f2bf(uv[0]); hv4.y = f2bf(uv[1]); hv4.z = f2bf(uv[2]); hv4.w = f2bf(uv[3]);
        *(ushort4*)&sUT[co*72 + r0] = hv4;
      }
    }
    __syncthreads();
    // kv GEMM: kv[m][c] += phi_k^T @ u ; A (phi_k^T) direct from global
    #pragma unroll
    for (int ks2 = 0; ks2 < 2; ks2++){
      bf16x8 ap[4], bu[2];
      #pragma unroll
      for (int mtp = 0; mtp < 4; mtp++)
        ap[mtp] = *(const bf16x8*)&phikt[(size_t)(b*MM + mtp*16 + l15)*NP + n0 + ks2*32 + quad*8];
      #pragma unroll
      for (int nt2 = 0; nt2 < 2; nt2++)
        bu[nt2] = *(const bf16x8*)&sUT[(wave*32 + nt2*16 + l15)*72 + ks2*32 + quad*8];
      #pragma unroll
      for (int mtp = 0; mtp < 4; mtp++)
        #pragma unroll
        for (int nt2 = 0; nt2 < 2; nt2++)
          kvacc[mtp][nt2] = __builtin_amdgcn_mfma_f32_16x16x32_bf16(ap[mtp], bu[nt2], kvacc[mtp][nt2], 0, 0, 0);
    }
  }
  float* kvb = kv + (size_t)(layer*BB + b)*MM*CC;
  #pragma unroll
  for (int mt = 0; mt < 4; mt++)
    #pragma unroll
    for (int nt2 = 0; nt2 < 2; nt2++)
      #pragma unroll
      for (int e = 0; e < 4; e++)
        atomicAdd(&kvb[(mt*16 + quad*4 + e)*CC + wave*32 + nt2*16 + l15], kvacc[mt][nt2][e]);
}

// ---------------- K4: repack kv -> bf16 [b][c(144)][m] (col 128 = ksum) -----
__global__ void k4_reduce(const float* kv, const float* ksum, u16* kvt, int layer){
  int b = blockIdx.x;
  int tid = threadIdx.x;  // 256
  const float* kvb = kv + (size_t)(layer*BB + b)*MM*CC;
  for (int idx = tid; idx < 144*MM; idx += 256){
    int c = idx >> 6, m = idx & 63;
    float v = (c < CC) ? kvb[m*CC + c] : ((c == CC) ? ksum[b*MM + m] : 0.f);
    kvt[(size_t)b*144*MM + idx] = f2bf(v);
  }
}

// ---------------- K5: num/den (den as 9th MFMA tile) + residual + LN --------
__global__ __launch_bounds__(256) void k5_attn(
    const u16* hin, u16* hout, const u16* phiq, const u16* kvt,
    const float* lng, const float* lnb, int layer)
{
  __shared__ u16 sH[64*132];       // residual in / normalized out (bf16)
  __shared__ u16 sKv[144*72];      // kv^T [c][m], col 128 = ksum, 129..143 = 0
  __shared__ float sLg[CC], sLb[CC];
  int tid = threadIdx.x;
  int b = blockIdx.y, n0 = blockIdx.x*64;
  int lane = tid & 63, wave = tid >> 6, quad = lane >> 4, l15 = lane & 15;
  for (int idx = tid; idx < 144*8; idx += 256){
    int c = idx >> 3, g = idx & 7;
    *(uint4*)&sKv[c*72 + g*8] = *(const uint4*)&kvt[(size_t)b*144*MM + c*MM + g*8];
  }
  if (tid < CC){ sLg[tid] = lng[layer*CC + tid]; sLb[tid] = lnb[layer*CC + tid]; }
  {
    int r = tid >> 2, seg = tid & 3;
    int n = n0 + r;
    const u16* src = hin + (size_t)(b*NN + min(n, NN-1))*CC + seg*32;
    #pragma unroll
    for (int k = 0; k < 32; k += 8){
      uint4 d = *(const uint4*)&src[k];
      *(uint2*)&sH[r*132 + seg*32 + k]     = make_uint2(d.x, d.y);
      *(uint2*)&sH[r*132 + seg*32 + k + 4] = make_uint2(d.z, d.w);
    }
  }
  __syncthreads();
  // A-frags: phi_q rows direct from global (wave owns rows wave*16..+15)
  bf16x8 aq[2];
  #pragma unroll
  for (int ks = 0; ks < 2; ks++)
    aq[ks] = *(const bf16x8*)&phiq[((size_t)(b*NN) + n0 + wave*16 + l15)*MM + ks*32 + quad*8];
  f32x4 nacc[9] = {};
  #pragma unroll
  for (int ks = 0; ks < 2; ks++)
    #pragma unroll
    for (int nt = 0; nt < 9; nt++){
      bf16x8 bk = *(const bf16x8*)&sKv[(nt*16 + l15)*72 + ks*32 + quad*8];
      nacc[nt] = __builtin_amdgcn_mfma_f32_16x16x32_bf16(aq[ks], bk, nacc[nt], 0, 0, 0);
    }
  // per-row: y = num/den + res ; LayerNorm via 16-lane shuffle reduce
  #pragma unroll
  for (int e = 0; e < 4; e++){
    float den = __shfl(nacc[8][e], lane & 48);   // broadcast from l15==0 of this quad
    int rml = wave*16 + quad*4 + e;
    float y[8];
    float s1 = 0.f, s2 = 0.f;
    #pragma unroll
    for (int nt = 0; nt < 8; nt++){
      float res = bf2f(sH[rml*132 + nt*16 + l15]);
      float yv = nacc[nt][e]/den + res;
      y[nt] = yv; s1 += yv; s2 += yv*yv;
    }
    #pragma unroll
    for (int off = 1; off < 16; off <<= 1){
      s1 += __shfl_xor(s1, off);
      s2 += __shfl_xor(s2, off);
    }
    float mu = s1 * (1.f/CC);
    float rs = rsqrtf(s2 * (1.f/CC) - mu*mu + 1e-5f);
    #pragma unroll
    for (int nt = 0; nt < 8; nt++){
      int c = nt*16 + l15;
      sH[rml*132 + c] = f2bf((y[nt] - mu)*rs*sLg[c] + sLb[c]);
    }
  }
  __syncthreads();
  {
    int r = tid >> 2, seg = tid & 3;
    int n = n0 + r;
    if (n < NN){
      u16* dst = hout + (size_t)(b*NN + n)*CC + seg*32;
      #pragma unroll
      for (int k = 0; k < 32; k += 8){
        uint2 a = *(const uint2*)&sH[r*132 + seg*32 + k];
        uint2 c2 = *(const uint2*)&sH[r*132 + seg*32 + k + 4];
        uint4 w = { a.x, a.y, c2.x, c2.y };
        *(uint4*)&dst[k] = w;
      }
    }
  }
}

// ---------------- K6: regression head + transpose ---------------------------
__global__ __launch_bounds__(256) void k6_final(
    const u16* skip, const u16* hbuf, const float* regw, const float* regb,
    float* out)
{
  __shared__ float sRW[PP*256];
  __shared__ float sRB[PP];
  int tid = threadIdx.x;
  for (int i = tid; i < PP*256; i += 256) sRW[i] = regw[i];
  if (tid < PP) sRB[tid] = regb[tid];
  __syncthreads();
  int b = blockIdx.y;
  int n = blockIdx.x*256 + tid;
  if (n >= NN) return;
  float acc[PP];
  #pragma unroll
  for (int p = 0; p < PP; p++) acc[p] = sRB[p];
  const u16* sr = skip + (size_t)(b*NN + n)*CC;
  const u16* hr = hbuf + (size_t)(b*NN + n)*CC;
  for (int half = 0; half < 2; half++){
    const u16* src = half ? hr : sr;
    int coff = half*128;
    for (int k = 0; k < CC; k += 8){
      uint4 d = *(const uint4*)&src[k];
      float v0 = __uint_as_float(d.x<<16), v1 = __uint_as_float(d.x & 0xffff0000u);
      float v2 = __uint_as_float(d.y<<16), v3 = __uint_as_float(d.y & 0xffff0000u);
      float v4 = __uint_as_float(d.z<<16), v5 = __uint_as_float(d.z & 0xffff0000u);
      float v6 = __uint_as_float(d.w<<16), v7 = __uint_as_float(d.w & 0xffff0000u);
      #pragma unroll
      for (int p = 0; p < PP; p++){
        const float* wr = &sRW[p*256 + coff + k];
        acc[p] += v0*wr[0] + v1*wr[1] + v2*wr[2] + v3*wr[3]
                + v4*wr[4] + v5*wr[5] + v6*wr[6] + v7*wr[7];
      }
    }
  }
  #pragma unroll
  for (int p = 0; p < PP; p++)
    out[(size_t)(b*PP + p)*NN + n] = acc[p];
}

// ---------------- launcher ---------------------------------------------------
extern "C" void kernel_launch(void* const* d_in, const int* in_sizes, int n_in,
                              void* d_out, int out_size, void* d_ws, size_t ws_size,
                              hipStream_t stream)
{
  const float* x        = (const float*)d_in[0];
  const float* xm       = (const float*)d_in[1];
  const float* node_emb = (const float*)d_in[2];
  const float* time_tab = (const float*)d_in[3];
  const float* week_tab = (const float*)d_in[4];
  const float* input_w  = (const float*)d_in[5];
  const float* input_b  = (const float*)d_in[6];
  const float* w1w      = (const float*)d_in[7];
  const float* w1b      = (const float*)d_in[8];
  const float* w2w      = (const float*)d_in[9];
  const float* w2b      = (const float*)d_in[10];
  const float* inw      = (const float*)d_in[11];
  const float* inb      = (const float*)d_in[12];
  const float* outw     = (const float*)d_in[13];
  const float* outb     = (const float*)d_in[14];
  const float* lng      = (const float*)d_in[15];
  const float* lnb      = (const float*)d_in[16];
  const float* regw     = (const float*)d_in[17];
  const float* regb     = (const float*)d_in[18];
  const float* proj     = (const float*)d_in[19];
  float* out = (float*)d_out;

  char* wsb = (char*)d_ws;
  size_t off = 0;
  auto alloc = [&](size_t bytes)->char*{
    char* p = wsb + off; off += (bytes + 255) & ~(size_t)255; return p;
  };
  u16*   skip  = (u16*)  alloc((size_t)BB*NN*CC*2);
  u16*   hbuf  = (u16*)  alloc((size_t)BB*NN*CC*2);
  u16*   phiq  = (u16*)  alloc((size_t)BB*NN*MM*2);
  u16*   phikt = (u16*)  alloc((size_t)BB*MM*NP*2 + 4096);
  float* sd1   = (float*)alloc((size_t)NN*MM*4);
  float* sd2   = (float*)alloc((size_t)NN*MM*4);
  float* sq1   = (float*)alloc((size_t)NN*4);
  float* sq2   = (float*)alloc((size_t)NN*4);
  float* cr1   = (float*)alloc((size_t)BB*NN*4);
  float* cr2   = (float*)alloc((size_t)BB*NN*4);
  u16*   wbf   = (u16*)  alloc((size_t)2*LL*CC*CC*2);
  float* kv    = (float*)alloc((size_t)LL*BB*MM*CC*4);
  u16*   kvt   = (u16*)  alloc((size_t)BB*144*MM*2);
  float* ksum  = (float*)alloc(BB*MM*4);
  float* bv1   = (float*)alloc(BB*DD*4);
  float* bv2   = (float*)alloc(BB*DD*4);
  float* sbd1  = (float*)alloc(BB*MM*4);
  float* sbd2  = (float*)alloc(BB*MM*4);
  float* bc1   = (float*)alloc(BB*4);
  float* bc2   = (float*)alloc(BB*4);
  float* mb    = (float*)alloc(BB*DD*4);
  int*   tod   = (int*)  alloc(BB*4);
  int*   dow   = (int*)  alloc(BB*4);
  unsigned* cmx= (unsigned*)alloc(MM*4);
  float* stab  = (float*)alloc(BB*4);
  (void)ws_size; (void)in_sizes; (void)n_in; (void)out_size;

  k0_prep<<<1, 512, 0, stream>>>(xm, time_tab, week_tab, w1w, w1b, w2w, w2b,
                                 input_w, input_b, proj,
                                 bv1, bv2, sbd1, sbd2, bc1, bc2, mb, tod, dow, cmx, ksum);
  k1_node<<<79, 256, 0, stream>>>(node_emb, w1w, w2w, proj, bv1, bv2, inw, outw,
                                  sd1, sd2, sq1, sq2, cr1, cr2, cmx, wbf, kv);
  k0b_stab<<<1, 64, 0, stream>>>(cmx, sbd2, stab);
  k1b_phi<<<dim3(79, 8), 256, 0, stream>>>(sd1, sd2, sq1, sq2, cr1, cr2,
                                           sbd1, sbd2, bc1, bc2, stab,
                                           phiq, phikt, ksum);
  k2_embed<<<dim3(79, 8), 256, 0, stream>>>(x, node_emb, time_tab, week_tab,
                                            input_w, mb, tod, dow, skip);
  for (int l = 0; l < LL; l++){
    const u16* hi = (l == 0) ? skip : hbuf;
    k3_gate<<<dim3(NB3, 8), 256, 0, stream>>>(hi, wbf, inb, outb, phikt, kv, l);
    k4_reduce<<<8, 256, 0, stream>>>(kv, ksum, kvt, l);
    k5_attn<<<dim3(NB5, 8), 256, 0, stream>>>(hi, hbuf, phiq, kvt, lng, lnb, l);
  }
  k6_final<<<dim3(79, 8), 256, 0, stream>>>(skip, hbuf, regw, regb, out);
}

// Round 4
// 661.058 us; speedup vs baseline: 1.8049x; 1.2149x over previous
//
#include <hip/hip_runtime.h>

typedef unsigned short u16;
typedef __attribute__((ext_vector_type(8))) __bf16 bf16x8;
typedef __attribute__((ext_vector_type(4))) float f32x4;

#define BB 8
#define TT 96
#define NN 20000
#define NP 20160          // padded n for phi_k^T (k3 reads up to 105*192=20160)
#define PP 12
#define LL 3
#define DD 32
#define CC 128
#define MM 64
#define NB3 105           // k3 blocks per batch (3 chunks of 64 rows each)
#define NB5 313           // k5 blocks per batch (1 chunk of 64 rows)
#define NB1 313           // k1 blocks (64 nodes each)

constexpr float KSC  = 0.8408964152537145f;   // 2 * 32^-0.25
constexpr float KSC2 = 0.7071067811865476f;   // KSC^2

__device__ inline u16 f2bf(float f){
  unsigned u = __float_as_uint(f);
  u = (u + 0x7fffu + ((u >> 16) & 1u)) >> 16;
  return (u16)u;
}
__device__ inline float bf2f(u16 h){ return __uint_as_float(((unsigned)h) << 16); }
__device__ inline unsigned fmapu(float f){
  unsigned u = __float_as_uint(f);
  return (u & 0x80000000u) ? ~u : (u | 0x80000000u);
}
__device__ inline float funmap(unsigned u){
  return (u & 0x80000000u) ? __uint_as_float(u & 0x7fffffffu) : __uint_as_float(~u);
}
__device__ inline unsigned pk2(float a, float b){
  return (unsigned)f2bf(a) | ((unsigned)f2bf(b) << 16);
}

// ---------------- K0: per-batch scalars + Q/E factor matrices ---------------
__global__ void k0_prep(const float* xm, const float* time_tab, const float* week_tab,
                        const float* w1w, const float* w1b, const float* w2w, const float* w2b,
                        const float* inw, const float* inb, const float* proj,
                        float* bv1, float* bv2, float* sbd1, float* sbd2,
                        float* bc1, float* bc2, float* mb, int* tod, int* dow,
                        unsigned* cmx, float* ksum, float* qmat, float* emat)
{
  __shared__ float sT[BB][DD], sWk[BB][DD];
  __shared__ float sB1[BB][DD], sB2[BB][DD];
  __shared__ float sW1G[DD][DD], sW2G[DD][DD], sPJ[MM][DD];
  __shared__ int sTod[BB], sDow[BB];
  int tid = threadIdx.x;  // 512
  ksum[tid] = 0.f;        // 8*64 == 512
  for (int i = tid; i < DD*DD; i += 512){
    int c = i >> 5, g = i & 31;
    sW1G[c][g] = w1w[c*96 + g];
    sW2G[c][g] = w2w[c*96 + g];
  }
  for (int i = tid; i < MM*DD; i += 512) sPJ[i >> 5][i & 31] = proj[i];
  if (tid < BB){
    float t0 = xm[(tid*TT + TT-1)*2 + 0];
    float t1 = xm[(tid*TT + TT-1)*2 + 1];
    int ti = (int)(t0 * (float)TT); ti = min(max(ti, 0), TT-1);
    int di = (int)(t1 * 7.0f);      di = min(max(di, 0), 6);
    sTod[tid] = ti; sDow[tid] = di; tod[tid] = ti; dow[tid] = di;
  }
  if (tid < MM) cmx[tid] = fmapu(-3e38f);
  __syncthreads();
  if (tid < BB*DD){
    int b = tid >> 5, g = tid & 31;
    sT[b][g]  = time_tab[sTod[b]*DD + g];
    sWk[b][g] = week_tab[sDow[b]*DD + g];
  }
  __syncthreads();
  {
    int which = tid >> 8, b = (tid >> 5) & 7, c = tid & 31;
    const float* w  = which ? w2w : w1w;
    const float* wb = which ? w2b : w1b;
    float s = wb[c];
    for (int g = 0; g < DD; g++)
      s += sT[b][g]*w[c*96 + 32 + g] + sWk[b][g]*w[c*96 + 64 + g];
    if (which){ bv2[b*DD+c] = s; sB2[b][c] = s; }
    else      { bv1[b*DD+c] = s; sB1[b][c] = s; }
  }
  __syncthreads();
  // Q factor: qmat[set][g][m] = KSC * sum_c W[c][g] * P[m][c]
  for (int e = tid; e < 2*DD*MM; e += 512){
    int set = e >> 11, g = (e >> 6) & 31, m = e & 63;
    float s = 0.f;
    if (set == 0){ for (int c = 0; c < DD; c++) s += sW1G[c][g]*sPJ[m][c]; }
    else         { for (int c = 0; c < DD; c++) s += sW2G[c][g]*sPJ[m][c]; }
    qmat[e] = KSC * s;
  }
  // E factor: emat[set][g][b] = KSC2 * sum_c W[c][g] * B[b][c]
  {
    int set = tid >> 8, g = (tid >> 3) & 31, b = tid & 7;
    float s = 0.f;
    if (set == 0){ for (int c = 0; c < DD; c++) s += sW1G[c][g]*sB1[b][c]; }
    else         { for (int c = 0; c < DD; c++) s += sW2G[c][g]*sB2[b][c]; }
    emat[tid] = KSC2 * s;
  }
  {
    int b = tid >> 6, m = tid & 63;
    float s1 = 0.f, s2 = 0.f;
    for (int c = 0; c < DD; c++){
      float p = sPJ[m][c];
      s1 += sB1[b][c]*p; s2 += sB2[b][c]*p;
    }
    sbd1[b*MM+m] = KSC * s1;
    sbd2[b*MM+m] = KSC * s2;
  }
  if (tid < 16){
    int b = tid & 7;
    float s = 0.f;
    if (tid >> 3){ for (int c = 0; c < DD; c++) s += sB2[b][c]*sB2[b][c]; bc2[b] = 0.5f*KSC2*s; }
    else         { for (int c = 0; c < DD; c++) s += sB1[b][c]*sB1[b][c]; bc1[b] = 0.5f*KSC2*s; }
  }
  if (tid < 256){
    int b = tid >> 5, c = tid & 31;
    float s = inb[c];
    for (int t = 0; t < TT; t++){
      float m0 = xm[(b*TT+t)*2+0], m1 = xm[(b*TT+t)*2+1];
      s += m0 * inw[c*288 + 96 + t] + m1 * inw[c*288 + 192 + t];
    }
    mb[b*DD+c] = s;
  }
}

// ---------------- K1: per-node tables via Q/E factors (4 threads/node) ------
__global__ __launch_bounds__(256) void k1_node(
    const float* node_emb, const float* w1w, const float* w2w,
    const float* qmat, const float* emat,
    const float* gin_w, const float* gout_w,
    float* sd1, float* sd2, float* sq1, float* sq2,
    float* cr1, float* cr2, unsigned* cmx,
    u16* wbf, float* kvz)
{
  __shared__ float sQ1[DD*MM], sQ2[DD*MM];    // [g][m]
  __shared__ float sW1[DD*DD], sW2[DD*DD];    // [c][g]
  __shared__ float sE[2*DD*BB];               // [set][g][b]
  __shared__ unsigned sCM[MM];
  int tid = threadIdx.x;
  int gid = blockIdx.x*256 + tid;
  const int TOT = NB1*256;
  for (int i = gid; i < LL*BB*MM*CC; i += TOT) kvz[i] = 0.f;
  for (int i = gid; i < 2*LL*CC*CC; i += TOT){
    int which = i / (LL*CC*CC);
    int r = i - which*(LL*CC*CC);
    wbf[i] = f2bf((which ? gout_w : gin_w)[r]);
  }
  for (int i = tid; i < DD*MM; i += 256){ sQ1[i] = qmat[i]; sQ2[i] = qmat[DD*MM + i]; }
  for (int i = tid; i < DD*DD; i += 256){
    sW1[i] = w1w[(i>>5)*96 + (i&31)];
    sW2[i] = w2w[(i>>5)*96 + (i&31)];
  }
  for (int i = tid; i < 2*DD*BB; i += 256) sE[i] = emat[i];   // FIX: full 512-load
  if (tid < MM) sCM[tid] = fmapu(-3e38f);
  __syncthreads();
  int r = tid >> 2, q = tid & 3;
  int n = blockIdx.x*64 + r;
  bool valid = n < NN;
  int nc = valid ? n : 0;
  float nd[DD];
  #pragma unroll
  for (int g = 0; g < DD; g += 4){
    float4 v = *(const float4*)&node_emb[nc*DD + g];
    nd[g] = v.x; nd[g+1] = v.y; nd[g+2] = v.z; nd[g+3] = v.w;
  }
  // sd1/sd2 for m in [q*16, q*16+16)
  float s1v[16], s2v[16];
  #pragma unroll
  for (int j = 0; j < 16; j++){ s1v[j] = 0.f; s2v[j] = 0.f; }
  #pragma unroll
  for (int g = 0; g < DD; g++){
    float xg = nd[g];
    #pragma unroll
    for (int jj = 0; jj < 16; jj += 4){
      float4 a1 = *(const float4*)&sQ1[g*MM + q*16 + jj];
      float4 a2 = *(const float4*)&sQ2[g*MM + q*16 + jj];
      s1v[jj+0] += xg*a1.x; s1v[jj+1] += xg*a1.y; s1v[jj+2] += xg*a1.z; s1v[jj+3] += xg*a1.w;
      s2v[jj+0] += xg*a2.x; s2v[jj+1] += xg*a2.y; s2v[jj+2] += xg*a2.z; s2v[jj+3] += xg*a2.w;
    }
  }
  if (valid){
    #pragma unroll
    for (int jj = 0; jj < 16; jj += 4){
      *(float4*)&sd1[(size_t)n*MM + q*16 + jj] = make_float4(s1v[jj], s1v[jj+1], s1v[jj+2], s1v[jj+3]);
      *(float4*)&sd2[(size_t)n*MM + q*16 + jj] = make_float4(s2v[jj], s2v[jj+1], s2v[jj+2], s2v[jj+3]);
    }
    #pragma unroll
    for (int j = 0; j < 16; j++)
      atomicMax(&sCM[q*16 + j], fmapu(s2v[j]));
  }
  // sq: channels [q*8, q*8+8) of r1/r2
  float sqp1 = 0.f, sqp2 = 0.f;
  #pragma unroll
  for (int c8 = 0; c8 < 8; c8++){
    int c = q*8 + c8;
    float d1 = 0.f, d2 = 0.f;
    #pragma unroll
    for (int g = 0; g < DD; g += 4){
      float4 w1v = *(const float4*)&sW1[c*DD + g];
      float4 w2v = *(const float4*)&sW2[c*DD + g];
      d1 += nd[g]*w1v.x + nd[g+1]*w1v.y + nd[g+2]*w1v.z + nd[g+3]*w1v.w;
      d2 += nd[g]*w2v.x + nd[g+1]*w2v.y + nd[g+2]*w2v.z + nd[g+3]*w2v.w;
    }
    sqp1 += d1*d1; sqp2 += d2*d2;
  }
  sqp1 += __shfl_xor(sqp1, 1); sqp1 += __shfl_xor(sqp1, 2);
  sqp2 += __shfl_xor(sqp2, 1); sqp2 += __shfl_xor(sqp2, 2);
  if (q == 0 && valid){
    sq1[n] = 0.5f*KSC2*sqp1;
    sq2[n] = 0.5f*KSC2*sqp2;
  }
  // cr: b-columns 2q, 2q+1 (E includes KSC2)
  {
    float cA1 = 0.f, cB1 = 0.f, cA2 = 0.f, cB2 = 0.f;
    #pragma unroll
    for (int g = 0; g < DD; g++){
      float xg = nd[g];
      cA1 += xg*sE[g*8 + 2*q];
      cB1 += xg*sE[g*8 + 2*q + 1];
      cA2 += xg*sE[256 + g*8 + 2*q];
      cB2 += xg*sE[256 + g*8 + 2*q + 1];
    }
    if (valid){
      cr1[(2*q)*NN + n]     = cA1;
      cr1[(2*q+1)*NN + n]   = cB1;
      cr2[(2*q)*NN + n]     = cA2;
      cr2[(2*q+1)*NN + n]   = cB2;
    }
  }
  __syncthreads();
  if (tid < MM) atomicMax(&cmx[tid], sCM[tid]);
}

// ---------------- K0b: key stabilizer ---------------------------------------
__global__ void k0b_stab(const unsigned* cmx, const float* sbd2, float* stab){
  int lane = threadIdx.x;  // 64
  float cm = funmap(cmx[lane]);
  for (int b = 0; b < BB; b++){
    float v = cm + sbd2[b*MM + lane];
    #pragma unroll
    for (int off = 32; off; off >>= 1) v = fmaxf(v, __shfl_xor(v, off));
    if (lane == 0) stab[b] = v;
  }
}

// ---------------- K1b: materialize phi_q [b][n][m], phi_k^T [b][m][NP], ksum
__global__ __launch_bounds__(256) void k1b_phi(
    const float* sd1, const float* sd2, const float* sq1, const float* sq2,
    const float* cr1, const float* cr2, const float* sbd1, const float* sbd2,
    const float* bc1, const float* bc2, const float* stab,
    u16* phiq, u16* phikt, float* ksum)
{
  __shared__ u16 sT[MM][264];     // phi_k^T tile [m][r], 256 rows + pad
  __shared__ float sQb[MM], sKb[MM];
  __shared__ float sRed[256];
  int tid = threadIdx.x;
  int b = blockIdx.y, n0 = blockIdx.x*256;
  if (tid < MM){
    sQb[tid] = sbd1[b*MM + tid];
    sKb[tid] = sbd2[b*MM + tid] - bc2[b] - stab[b];
  }
  __syncthreads();
  int n = n0 + tid;
  bool v = n < NN;
  int nc = v ? n : 0;
  float dq[MM];
  const float* s1r = sd1 + (size_t)nc*MM;
  #pragma unroll
  for (int m = 0; m < MM; m += 4){
    float4 t = *(const float4*)&s1r[m];
    dq[m]=t.x; dq[m+1]=t.y; dq[m+2]=t.z; dq[m+3]=t.w;
  }
  float rm = -3e38f;
  #pragma unroll
  for (int m = 0; m < MM; m++) rm = fmaxf(rm, dq[m] + sQb[m]);
  float diagq = sq1[nc] + cr1[b*NN + nc] + bc1[b];
  u16* pqr = phiq + ((size_t)(b*NN) + nc)*MM;
  #pragma unroll
  for (int m = 0; m < MM; m += 8){
    float p[8];
    #pragma unroll
    for (int j = 0; j < 8; j++){
      float ev = dq[m+j] + sQb[m+j] - rm - diagq;
      p[j] = 0.125f*__expf(ev) + 1.25e-7f;
    }
    uint4 w = { pk2(p[0],p[1]), pk2(p[2],p[3]), pk2(p[4],p[5]), pk2(p[6],p[7]) };
    if (v) *(uint4*)&pqr[m] = w;
  }
  // phi_k -> transposed LDS tile (zero for padded rows)
  const float* s2r = sd2 + (size_t)nc*MM;
  float diagk = sq2[nc] + cr2[b*NN + nc];
  #pragma unroll
  for (int m = 0; m < MM; m++){
    float ev = s2r[m] + sKb[m] - diagk;
    float pv = v ? (0.125f*__expf(ev) + 1.25e-7f) : 0.f;
    sT[m][tid] = f2bf(pv);
  }
  __syncthreads();
  {
    int m = tid >> 2, q = tid & 3;
    float s = 0.f;
    for (int j = 0; j < 64; j++) s += bf2f(sT[m][q*64 + j]);
    sRed[tid] = s;
  }
  __syncthreads();
  if (tid < MM){
    float s = sRed[tid*4] + sRed[tid*4+1] + sRed[tid*4+2] + sRed[tid*4+3];
    atomicAdd(&ksum[b*MM + tid], s);
  }
  {
    int m = tid >> 2, q = tid & 3;
    int nb = n0 + q*64;
    if (nb + 64 <= NP){
      u16* dst = phikt + (size_t)(b*MM + m)*NP + nb;
      #pragma unroll
      for (int j = 0; j < 64; j += 8)
        *(uint4*)&dst[j] = *(const uint4*)&sT[m][q*64 + j];
    }
  }
}

// ---------------- K2: input embedding -> skip (bf16) ------------------------
__global__ __launch_bounds__(256) void k2_embed(
    const float* x, const float* node_emb, const float* time_tab, const float* week_tab,
    const float* inw, const float* mb, const int* tod, const int* dow,
    u16* skip)
{
  __shared__ float sWt[TT*DD];          // [t][c]
  __shared__ float sMB[DD], sTE[DD], sWE[DD];
  int tid = threadIdx.x;
  int b = blockIdx.y;
  for (int i = tid; i < TT*DD; i += 256){
    int t = i >> 5, c = i & 31;
    sWt[i] = inw[c*288 + t];
  }
  if (tid < DD){
    sMB[tid] = mb[b*DD + tid];
    sTE[tid] = time_tab[tod[b]*DD + tid];
    sWE[tid] = week_tab[dow[b]*DD + tid];
  }
  __syncthreads();
  int n = blockIdx.x*256 + tid;
  bool valid = n < NN;
  int nc = valid ? n : 0;
  float acc[DD];
  #pragma unroll
  for (int c = 0; c < DD; c++) acc[c] = sMB[c];
  const float* xb = x + (size_t)b*TT*NN + nc;
  for (int t = 0; t < TT; t++){
    float xv = xb[(size_t)t*NN];
    #pragma unroll
    for (int c = 0; c < DD; c++) acc[c] += xv * sWt[t*DD + c];
  }
  if (!valid) return;
  float nodev[DD];
  #pragma unroll
  for (int g = 0; g < DD; g += 4){
    float4 v = *(const float4*)&node_emb[n*DD + g];
    nodev[g] = v.x; nodev[g+1] = v.y; nodev[g+2] = v.z; nodev[g+3] = v.w;
  }
  auto chv = [&](int c)->float{
    if (c < 32)  return acc[c];
    if (c < 64)  return nodev[c-32];
    if (c < 96)  return sTE[c-64];
    return sWE[c-96];
  };
  u16* dst = skip + (size_t)(b*NN + n)*CC;
  #pragma unroll
  for (int g = 0; g < CC; g += 8){
    uint4 w;
    w.x = pk2(chv(g+0), chv(g+1));
    w.y = pk2(chv(g+2), chv(g+3));
    w.z = pk2(chv(g+4), chv(g+5));
    w.w = pk2(chv(g+6), chv(g+7));
    *(uint4*)&dst[g] = w;
  }
}

// ---------------- K3: gated projections + kv atomic accumulate (MFMA) -------
__global__ __launch_bounds__(256,2) void k3_gate(
    const u16* hin, const u16* wbf, const float* inb, const float* outb,
    const u16* phikt, float* kv, int layer)
{
  __shared__ u16 sUT[CC*72];       // gated u, transposed [c][r]
  __shared__ float s_inb[CC], s_outb[CC];
  int tid = threadIdx.x;
  int b = blockIdx.y, blk = blockIdx.x;
  int lane = tid & 63, wave = tid >> 6, quad = lane >> 4, l15 = lane & 15;
  if (tid < CC){ s_inb[tid] = inb[layer*CC + tid]; s_outb[tid] = outb[layer*CC + tid]; }

  // per-wave weight B-fragments in registers: bw[ks][nt]
  bf16x8 bw[4][4];
  #pragma unroll
  for (int nt = 0; nt < 4; nt++){
    int which = nt >> 1;
    int co = wave*32 + (nt & 1)*16 + l15;
    const u16* wp = wbf + ((size_t)(which*LL + layer)*CC + co)*CC;
    #pragma unroll
    for (int ks = 0; ks < 4; ks++)
      bw[ks][nt] = *(const bf16x8*)&wp[ks*32 + quad*8];
  }
  f32x4 kvacc[4][2] = {};
  const u16* hbase = hin + (size_t)(b*NN)*CC;

  for (int ch = 0; ch < 3; ch++){
    int n0 = blk*192 + ch*64;
    // gate GEMM: A from global (row-major == A-frag layout), B in regs
    f32x4 acc[4][4] = {};
    bf16x8 af[2][4];
    #pragma unroll
    for (int mt = 0; mt < 4; mt++)
      af[0][mt] = *(const bf16x8*)&hbase[(size_t)(n0 + mt*16 + l15)*CC + quad*8];
    #pragma unroll
    for (int ks = 0; ks < 4; ks++){
      int cur = ks & 1, nxt = cur ^ 1;
      if (ks < 3){
        #pragma unroll
        for (int mt = 0; mt < 4; mt++)
          af[nxt][mt] = *(const bf16x8*)&hbase[(size_t)(n0 + mt*16 + l15)*CC + (ks+1)*32 + quad*8];
      }
      #pragma unroll
      for (int mt = 0; mt < 4; mt++)
        #pragma unroll
        for (int nt = 0; nt < 4; nt++)
          acc[mt][nt] = __builtin_amdgcn_mfma_f32_16x16x32_bf16(af[cur][mt], bw[ks][nt], acc[mt][nt], 0, 0, 0);
    }
    __syncthreads();   // previous chunk's sUT fully consumed
    // gating -> sUT (transposed [c][r])
    #pragma unroll
    for (int mt = 0; mt < 4; mt++){
      int r0 = mt*16 + quad*4;
      #pragma unroll
      for (int nt = 0; nt < 2; nt++){
        int co = wave*32 + nt*16 + l15;
        float bi = s_inb[co], bo = s_outb[co];
        float uv[4];
        #pragma unroll
        for (int e = 0; e < 4; e++){
          float up = acc[mt][nt][e] + bi;
          float vp = acc[mt][nt+2][e] + bo;
          float u = vp / (1.f + __expf(-up));
          if (n0 + r0 + e >= NN) u = 0.f;
          uv[e] = u;
        }
        ushort4 hv4;
        hv4.x = f2bf(uv[0]); hv4.y = f2bf(uv[1]); hv4.z = f2bf(uv[2]); hv4.w = f2bf(uv[3]);
        *(ushort4*)&sUT[co*72 + r0] = hv4;
      }
    }
    __syncthreads();
    // kv GEMM: kv[m][c] += phi_k^T @ u ; A (phi_k^T) direct from global
    #pragma unroll
    for (int ks2 = 0; ks2 < 2; ks2++){
      bf16x8 ap[4], bu[2];
      #pragma unroll
      for (int mtp = 0; mtp < 4; mtp++)
        ap[mtp] = *(const bf16x8*)&phikt[(size_t)(b*MM + mtp*16 + l15)*NP + n0 + ks2*32 + quad*8];
      #pragma unroll
      for (int nt2 = 0; nt2 < 2; nt2++)
        bu[nt2] = *(const bf16x8*)&sUT[(wave*32 + nt2*16 + l15)*72 + ks2*32 + quad*8];
      #pragma unroll
      for (int mtp = 0; mtp < 4; mtp++)
        #pragma unroll
        for (int nt2 = 0; nt2 < 2; nt2++)
          kvacc[mtp][nt2] = __builtin_amdgcn_mfma_f32_16x16x32_bf16(ap[mtp], bu[nt2], kvacc[mtp][nt2], 0, 0, 0);
    }
  }
  float* kvb = kv + (size_t)(layer*BB + b)*MM*CC;
  #pragma unroll
  for (int mt = 0; mt < 4; mt++)
    #pragma unroll
    for (int nt2 = 0; nt2 < 2; nt2++)
      #pragma unroll
      for (int e = 0; e < 4; e++)
        atomicAdd(&kvb[(mt*16 + quad*4 + e)*CC + wave*32 + nt2*16 + l15], kvacc[mt][nt2][e]);
}

// ---------------- K4: repack kv -> bf16 [b][c(144)][m] (col 128 = ksum) -----
__global__ void k4_reduce(const float* kv, const float* ksum, u16* kvt, int layer){
  int b = blockIdx.x;
  int tid = threadIdx.x;  // 256
  const float* kvb = kv + (size_t)(layer*BB + b)*MM*CC;
  for (int idx = tid; idx < 144*MM; idx += 256){
    int c = idx >> 6, m = idx & 63;
    float v = (c < CC) ? kvb[m*CC + c] : ((c == CC) ? ksum[b*MM + m] : 0.f);
    kvt[(size_t)b*144*MM + idx] = f2bf(v);
  }
}

// ---------------- K5: num/den (den as 9th MFMA tile) + residual + LN --------
__global__ __launch_bounds__(256) void k5_attn(
    const u16* hin, u16* hout, const u16* phiq, const u16* kvt,
    const float* lng, const float* lnb, int layer)
{
  __shared__ u16 sH[64*132];       // residual in / normalized out (bf16)
  __shared__ u16 sKv[144*72];      // kv^T [c][m], col 128 = ksum, 129..143 = 0
  __shared__ float sLg[CC], sLb[CC];
  int tid = threadIdx.x;
  int b = blockIdx.y, n0 = blockIdx.x*64;
  int lane = tid & 63, wave = tid >> 6, quad = lane >> 4, l15 = lane & 15;
  for (int idx = tid; idx < 144*8; idx += 256){
    int c = idx >> 3, g = idx & 7;
    *(uint4*)&sKv[c*72 + g*8] = *(const uint4*)&kvt[(size_t)b*144*MM + c*MM + g*8];
  }
  if (tid < CC){ sLg[tid] = lng[layer*CC + tid]; sLb[tid] = lnb[layer*CC + tid]; }
  {
    int r = tid >> 2, seg = tid & 3;
    int n = n0 + r;
    const u16* src = hin + (size_t)(b*NN + min(n, NN-1))*CC + seg*32;
    #pragma unroll
    for (int k = 0; k < 32; k += 8){
      uint4 d = *(const uint4*)&src[k];
      *(uint2*)&sH[r*132 + seg*32 + k]     = make_uint2(d.x, d.y);
      *(uint2*)&sH[r*132 + seg*32 + k + 4] = make_uint2(d.z, d.w);
    }
  }
  __syncthreads();
  // A-frags: phi_q rows direct from global (wave owns rows wave*16..+15)
  bf16x8 aq[2];
  #pragma unroll
  for (int ks = 0; ks < 2; ks++)
    aq[ks] = *(const bf16x8*)&phiq[((size_t)(b*NN) + n0 + wave*16 + l15)*MM + ks*32 + quad*8];
  f32x4 nacc[9] = {};
  #pragma unroll
  for (int ks = 0; ks < 2; ks++)
    #pragma unroll
    for (int nt = 0; nt < 9; nt++){
      bf16x8 bk = *(const bf16x8*)&sKv[(nt*16 + l15)*72 + ks*32 + quad*8];
      nacc[nt] = __builtin_amdgcn_mfma_f32_16x16x32_bf16(aq[ks], bk, nacc[nt], 0, 0, 0);
    }
  // per-row: y = num/den + res ; LayerNorm via 16-lane shuffle reduce
  #pragma unroll
  for (int e = 0; e < 4; e++){
    float den = __shfl(nacc[8][e], lane & 48);   // broadcast from l15==0 of this quad
    int rml = wave*16 + quad*4 + e;
    float y[8];
    float s1 = 0.f, s2 = 0.f;
    #pragma unroll
    for (int nt = 0; nt < 8; nt++){
      float res = bf2f(sH[rml*132 + nt*16 + l15]);
      float yv = nacc[nt][e]/den + res;
      y[nt] = yv; s1 += yv; s2 += yv*yv;
    }
    #pragma unroll
    for (int off = 1; off < 16; off <<= 1){
      s1 += __shfl_xor(s1, off);
      s2 += __shfl_xor(s2, off);
    }
    float mu = s1 * (1.f/CC);
    float rs = rsqrtf(s2 * (1.f/CC) - mu*mu + 1e-5f);
    #pragma unroll
    for (int nt = 0; nt < 8; nt++){
      int c = nt*16 + l15;
      sH[rml*132 + c] = f2bf((y[nt] - mu)*rs*sLg[c] + sLb[c]);
    }
  }
  __syncthreads();
  {
    int r = tid >> 2, seg = tid & 3;
    int n = n0 + r;
    if (n < NN){
      u16* dst = hout + (size_t)(b*NN + n)*CC + seg*32;
      #pragma unroll
      for (int k = 0; k < 32; k += 8){
        uint2 a = *(const uint2*)&sH[r*132 + seg*32 + k];
        uint2 c2 = *(const uint2*)&sH[r*132 + seg*32 + k + 4];
        uint4 w = { a.x, a.y, c2.x, c2.y };
        *(uint4*)&dst[k] = w;
      }
    }
  }
}

// ---------------- K6: regression head + transpose ---------------------------
__global__ __launch_bounds__(256) void k6_final(
    const u16* skip, const u16* hbuf, const float* regw, const float* regb,
    float* out)
{
  __shared__ float sRW[PP*256];
  __shared__ float sRB[PP];
  int tid = threadIdx.x;
  for (int i = tid; i < PP*256; i += 256) sRW[i] = regw[i];
  if (tid < PP) sRB[tid] = regb[tid];
  __syncthreads();
  int b = blockIdx.y;
  int n = blockIdx.x*256 + tid;
  if (n >= NN) return;
  float acc[PP];
  #pragma unroll
  for (int p = 0; p < PP; p++) acc[p] = sRB[p];
  const u16* sr = skip + (size_t)(b*NN + n)*CC;
  const u16* hr = hbuf + (size_t)(b*NN + n)*CC;
  for (int half = 0; half < 2; half++){
    const u16* src = half ? hr : sr;
    int coff = half*128;
    for (int k = 0; k < CC; k += 8){
      uint4 d = *(const uint4*)&src[k];
      float v0 = __uint_as_float(d.x<<16), v1 = __uint_as_float(d.x & 0xffff0000u);
      float v2 = __uint_as_float(d.y<<16), v3 = __uint_as_float(d.y & 0xffff0000u);
      float v4 = __uint_as_float(d.z<<16), v5 = __uint_as_float(d.z & 0xffff0000u);
      float v6 = __uint_as_float(d.w<<16), v7 = __uint_as_float(d.w & 0xffff0000u);
      #pragma unroll
      for (int p = 0; p < PP; p++){
        const float* wr = &sRW[p*256 + coff + k];
        acc[p] += v0*wr[0] + v1*wr[1] + v2*wr[2] + v3*wr[3]
                + v4*wr[4] + v5*wr[5] + v6*wr[6] + v7*wr[7];
      }
    }
  }
  #pragma unroll
  for (int p = 0; p < PP; p++)
    out[(size_t)(b*PP + p)*NN + n] = acc[p];
}

// ---------------- launcher ---------------------------------------------------
extern "C" void kernel_launch(void* const* d_in, const int* in_sizes, int n_in,
                              void* d_out, int out_size, void* d_ws, size_t ws_size,
                              hipStream_t stream)
{
  const float* x        = (const float*)d_in[0];
  const float* xm       = (const float*)d_in[1];
  const float* node_emb = (const float*)d_in[2];
  const float* time_tab = (const float*)d_in[3];
  const float* week_tab = (const float*)d_in[4];
  const float* input_w  = (const float*)d_in[5];
  const float* input_b  = (const float*)d_in[6];
  const float* w1w      = (const float*)d_in[7];
  const float* w1b      = (const float*)d_in[8];
  const float* w2w      = (const float*)d_in[9];
  const float* w2b      = (const float*)d_in[10];
  const float* inw      = (const float*)d_in[11];
  const float* inb      = (const float*)d_in[12];
  const float* outw     = (const float*)d_in[13];
  const float* outb     = (const float*)d_in[14];
  const float* lng      = (const float*)d_in[15];
  const float* lnb      = (const float*)d_in[16];
  const float* regw     = (const float*)d_in[17];
  const float* regb     = (const float*)d_in[18];
  const float* proj     = (const float*)d_in[19];
  float* out = (float*)d_out;

  char* wsb = (char*)d_ws;
  size_t off = 0;
  auto alloc = [&](size_t bytes)->char*{
    char* p = wsb + off; off += (bytes + 255) & ~(size_t)255; return p;
  };
  u16*   skip  = (u16*)  alloc((size_t)BB*NN*CC*2);
  u16*   hbuf  = (u16*)  alloc((size_t)BB*NN*CC*2);
  u16*   phiq  = (u16*)  alloc((size_t)BB*NN*MM*2);
  u16*   phikt = (u16*)  alloc((size_t)BB*MM*NP*2 + 4096);
  float* sd1   = (float*)alloc((size_t)NN*MM*4);
  float* sd2   = (float*)alloc((size_t)NN*MM*4);
  float* sq1   = (float*)alloc((size_t)NN*4);
  float* sq2   = (float*)alloc((size_t)NN*4);
  float* cr1   = (float*)alloc((size_t)BB*NN*4);
  float* cr2   = (float*)alloc((size_t)BB*NN*4);
  u16*   wbf   = (u16*)  alloc((size_t)2*LL*CC*CC*2);
  float* kv    = (float*)alloc((size_t)LL*BB*MM*CC*4);
  u16*   kvt   = (u16*)  alloc((size_t)BB*144*MM*2);
  float* ksum  = (float*)alloc(BB*MM*4);
  float* bv1   = (float*)alloc(BB*DD*4);
  float* bv2   = (float*)alloc(BB*DD*4);
  float* sbd1  = (float*)alloc(BB*MM*4);
  float* sbd2  = (float*)alloc(BB*MM*4);
  float* bc1   = (float*)alloc(BB*4);
  float* bc2   = (float*)alloc(BB*4);
  float* mb    = (float*)alloc(BB*DD*4);
  int*   tod   = (int*)  alloc(BB*4);
  int*   dow   = (int*)  alloc(BB*4);
  unsigned* cmx= (unsigned*)alloc(MM*4);
  float* stab  = (float*)alloc(BB*4);
  float* qmat  = (float*)alloc(2*DD*MM*4);
  float* emat  = (float*)alloc(2*DD*BB*4);
  (void)ws_size; (void)in_sizes; (void)n_in; (void)out_size;

  k0_prep<<<1, 512, 0, stream>>>(xm, time_tab, week_tab, w1w, w1b, w2w, w2b,
                                 input_w, input_b, proj,
                                 bv1, bv2, sbd1, sbd2, bc1, bc2, mb, tod, dow, cmx, ksum,
                                 qmat, emat);
  k1_node<<<NB1, 256, 0, stream>>>(node_emb, w1w, w2w, qmat, emat, inw, outw,
                                   sd1, sd2, sq1, sq2, cr1, cr2, cmx, wbf, kv);
  k0b_stab<<<1, 64, 0, stream>>>(cmx, sbd2, stab);
  k1b_phi<<<dim3(79, 8), 256, 0, stream>>>(sd1, sd2, sq1, sq2, cr1, cr2,
                                           sbd1, sbd2, bc1, bc2, stab,
                                           phiq, phikt, ksum);
  k2_embed<<<dim3(79, 8), 256, 0, stream>>>(x, node_emb, time_tab, week_tab,
                                            input_w, mb, tod, dow, skip);
  for (int l = 0; l < LL; l++){
    const u16* hi = (l == 0) ? skip : hbuf;
    k3_gate<<<dim3(NB3, 8), 256, 0, stream>>>(hi, wbf, inb, outb, phikt, kv, l);
    k4_reduce<<<8, 256, 0, stream>>>(kv, ksum, kvt, l);
    k5_attn<<<dim3(NB5, 8), 256, 0, stream>>>(hi, hbuf, phiq, kvt, lng, lnb, l);
  }
  k6_final<<<dim3(79, 8), 256, 0, stream>>>(skip, hbuf, regw, regb, out);
}